// Round 7
// baseline (375.035 us; speedup 1.0000x reference)
//
#include <hip/hip_runtime.h>

#define HIDDEN 2048
#define INTER  5632
#define TOKENS 4096

#define BM 128
#define BN 128
#define BK 64
#define NT2 (INTER / BK)   // 88 K-tiles for gemm2

#define G1B ((TOKENS / BM) * (INTER / BN))   // 1408 gemm1 blocks
#define WDB 352                               // Wd-dequant trailing blocks

using bf16x8 = __attribute__((ext_vector_type(8))) __bf16;
using f32x4  = __attribute__((ext_vector_type(4))) float;

__device__ __forceinline__ unsigned short f2bf(float f) {
    unsigned int u = __float_as_uint(f);
    u += 0x7FFFu + ((u >> 16) & 1u);
    return (unsigned short)(u >> 16);
}

#define GLDS(gptr, lptr) \
    __builtin_amdgcn_global_load_lds((__attribute__((address_space(1))) void*)(gptr), \
                                     (__attribute__((address_space(3))) void*)(lptr), 16, 0, 0)

// Journal:
// R2: XOR-swizzle conflict-free w/ 16x16 frags. R5: group-raster FETCH -30%.
// R8: 32x32 frags 4-way bank-conflict at BK=64 — 16x16 only. R3: (256,3)
// gemm1 spills. R4: BK=32 dbuf regressed. R6: barrier-free glds UNSAFE.
// R9 FAILED: 8-phase port (1 blk/CU): 48->31%, 176->252us.
// R10 FAILED: min-2-phase 256x128 @ 1 blk/CU: 36%, 219us (128KB LDS kills
//   2-blk de-phasing). R11: gemm1=R0 verified; gemm2 counted-vmcnt NEUTRAL.
// R12 DIAG: gemm1 2-way split +45us (dispatch-round tails are first-order);
//   prep,gemm2 each <109, sum ~188 incl gaps.
// R13 FAILED: L2-gather prep +12us (lane-divergent gather >> LDS gather).
// R14: ILP-16 idx preload: recovered R13 loss, ~0 vs original R7 prep ->
//   prep is NOT idx-latency-bound. Bottom-up models predict ~20us, measure
//   ~90: model wrong somewhere structural, stop micro-tuning prep.
// R15 (this round): LAUNCH-STRUCTURE overlap.
//   (a) Wd-dequant (needed only by gemm2) merged into gemm1 as trailing
//       blocks -> fills gemm1 tail round + stall slots. smem aliased
//       (48KB tiles | 64KB codebook) keeps 2 blk/CU.
//   (b) x-cast split into LDS-free kernel (was paying 64KB/block for
//       nothing -> occupancy 2->4 blk/CU).
//   (c) prep keeps only Wg/Wu dequant (352 blocks).
// ---------------------------------------------------------------------

// ---------------- cast x: fp32 -> bf16, no LDS ----------------
__global__ __launch_bounds__(512) void cast_kernel(const float* __restrict__ x,
                                                   unsigned short* __restrict__ xb) {
    int t = blockIdx.x * 512 + threadIdx.x;
    const float4* x4 = (const float4*)x;
    float4 a = x4[2 * t];
    float4 c = x4[2 * t + 1];
    uint4 o;
    o.x = f2bf(a.x) | ((unsigned int)f2bf(a.y) << 16);
    o.y = f2bf(a.z) | ((unsigned int)f2bf(a.w) << 16);
    o.z = f2bf(c.x) | ((unsigned int)f2bf(c.y) << 16);
    o.w = f2bf(c.z) | ((unsigned int)f2bf(c.w) << 16);
    ((uint4*)xb)[t] = o;
}

// ---------------- prep: dequant Wg, Wu only (LDS codebook) ----------------
__global__ __launch_bounds__(512) void prep_kernel(
        const int* __restrict__ ig, const float* __restrict__ cbg,
        const float* __restrict__ sg, unsigned short* __restrict__ wg,
        const int* __restrict__ iu, const float* __restrict__ cbu,
        const float* __restrict__ su, unsigned short* __restrict__ wu) {
    __shared__ unsigned short cbl[4096 * 8];   // 64 KB bf16 codebook
    const int b = blockIdx.x;
    const int tid = threadIdx.x;

    const int mat = b / 176;
    const int bl  = b % 176;
    const int* idx; const float* cb; const float* scale; unsigned short* w;
    if (mat == 0) { idx = ig; cb = cbg; scale = sg; w = wg; }
    else          { idx = iu; cb = cbu; scale = su; w = wu; }
    const int ncol8 = HIDDEN / 8;

    const size_t base = (size_t)bl * 8192;

    // batched idx/scale preload (R14): HBM chains hide under staging
    int   ids[16];
    float ss[16];
#pragma unroll
    for (int i = 0; i < 16; ++i) {
        size_t t = base + i * 512 + tid;
        ids[i] = idx[t];
        ss[i]  = scale[t / ncol8];
    }

#pragma unroll
    for (int i = 0; i < 8; ++i) {
        int r = i * 512 + tid;
        const float4* c4 = (const float4*)(cb + ((size_t)r << 3));
        float4 a = c4[0];
        float4 c = c4[1];
        uint4 o;
        o.x = f2bf(a.x) | ((unsigned int)f2bf(a.y) << 16);
        o.y = f2bf(a.z) | ((unsigned int)f2bf(a.w) << 16);
        o.z = f2bf(c.x) | ((unsigned int)f2bf(c.y) << 16);
        o.w = f2bf(c.z) | ((unsigned int)f2bf(c.w) << 16);
        ((uint4*)cbl)[r] = o;
    }
    __syncthreads();

#pragma unroll
    for (int i = 0; i < 16; ++i) {
        size_t t = base + i * 512 + tid;
        const unsigned short* cw = cbl + ((unsigned)ids[i] << 3);
        uint4 cv = *(const uint4*)cw;
        float s = ss[i];
        unsigned int ww[4];
#pragma unroll
        for (int j = 0; j < 4; ++j) {
            unsigned int pair = (&cv.x)[j];
            float lo = __uint_as_float(pair << 16) * s;
            float hi = __uint_as_float(pair & 0xFFFF0000u) * s;
            ww[j] = f2bf(lo) | ((unsigned int)f2bf(hi) << 16);
        }
        uint4 o = {ww[0], ww[1], ww[2], ww[3]};
        ((uint4*)w)[t] = o;
    }
}

__device__ __forceinline__ void decode_block(int bid, int nblocks_m, int nblocks_n,
                                             int gN, int* mb, int* nb) {
    int gw = nblocks_m * gN;
    int group = bid / gw;
    int inb = bid % gw;
    int gn = group * gN;
    int width = (nblocks_n - gn < gN) ? (nblocks_n - gn) : gN;
    *mb = inb / width;
    *nb = gn + inb % width;
}

// ---------------- GEMM1 + trailing Wd-dequant blocks ----------------
// bid < G1B: R0-exact gemm1 (128x128, 2-barrier, verified 173.5us/49%).
// bid >= G1B: Wd dequant (256 thr, 16 codes/thr) — consumed only by gemm2,
// so stream-order makes this race-free; fills gemm1's tail round.
__global__ __launch_bounds__(256, 2) void gemm1_kernel(const unsigned short* __restrict__ X,
                                                       const unsigned short* __restrict__ Wg,
                                                       const unsigned short* __restrict__ Wu,
                                                       unsigned short* __restrict__ H,
                                                       const int* __restrict__ idn,
                                                       const float* __restrict__ cbd,
                                                       const float* __restrict__ sd,
                                                       unsigned short* __restrict__ Wd) {
    __shared__ unsigned short smem[32768];   // 64 KB: tiles (48KB) | codebook (64KB)

    const int tid  = threadIdx.x;

    if (blockIdx.x >= G1B) {
        // ---------- Wd dequant ----------
        const int bl = blockIdx.x - G1B;          // 0..351
        const size_t base = (size_t)bl * 4096;    // 352*4096 = 1.44M codes
        const int ncol8 = INTER / 8;              // 704

        int   ids[16];
        float ss[16];
#pragma unroll
        for (int i = 0; i < 16; ++i) {
            size_t t = base + i * 256 + tid;
            ids[i] = idn[t];
            ss[i]  = sd[t / ncol8];
        }
#pragma unroll
        for (int i = 0; i < 16; ++i) {            // 4096 entries / 256 thr
            int r = i * 256 + tid;
            const float4* c4 = (const float4*)(cbd + ((size_t)r << 3));
            float4 a = c4[0];
            float4 c = c4[1];
            uint4 o;
            o.x = f2bf(a.x) | ((unsigned int)f2bf(a.y) << 16);
            o.y = f2bf(a.z) | ((unsigned int)f2bf(a.w) << 16);
            o.z = f2bf(c.x) | ((unsigned int)f2bf(c.y) << 16);
            o.w = f2bf(c.z) | ((unsigned int)f2bf(c.w) << 16);
            ((uint4*)smem)[r] = o;
        }
        __syncthreads();
#pragma unroll
        for (int i = 0; i < 16; ++i) {
            size_t t = base + i * 256 + tid;
            const unsigned short* cw = smem + ((unsigned)ids[i] << 3);
            uint4 cv = *(const uint4*)cw;
            float s = ss[i];
            unsigned int ww[4];
#pragma unroll
            for (int j = 0; j < 4; ++j) {
                unsigned int pair = (&cv.x)[j];
                float lo = __uint_as_float(pair << 16) * s;
                float hi = __uint_as_float(pair & 0xFFFF0000u) * s;
                ww[j] = f2bf(lo) | ((unsigned int)f2bf(hi) << 16);
            }
            uint4 o = {ww[0], ww[1], ww[2], ww[3]};
            ((uint4*)Wd)[t] = o;
        }
        return;
    }

    // ---------- gemm1 (R0-exact body, smem-aliased tiles) ----------
    unsigned short* As  = smem;            // 16 KB
    unsigned short* Bgs = smem + 8192;     // 16 KB
    unsigned short* Bus = smem + 16384;    // 16 KB

    const int lane = tid & 63;
    const int wave = tid >> 6;
    int mb, nb;
    decode_block(blockIdx.x, TOKENS / BM, INTER / BN, 4, &mb, &nb);
    const int m0 = mb * BM;
    const int n0 = nb * BN;

    const int srow = tid >> 3;
    const int scol = (tid & 7) << 3;
    const int gcol = (((tid & 7) ^ (srow & 7))) << 3;

    const int wr = wave >> 1;
    const int wc = wave & 1;
    const int ln15 = lane & 15;
    const int lq = lane >> 4;
    const int swr = ln15 & 7;

    f32x4 accg[4][4], accu[4][4];
    const f32x4 z = {0.f, 0.f, 0.f, 0.f};
    for (int i = 0; i < 4; ++i)
        for (int j = 0; j < 4; ++j) { accg[i][j] = z; accu[i][j] = z; }

    for (int kt = 0; kt < HIDDEN / BK; ++kt) {
        const int k0 = kt * BK;
        __syncthreads();
#pragma unroll
        for (int i = 0; i < 4; ++i) {
            const int r = i * 32 + srow;
            GLDS(X  + (size_t)(m0 + r) * HIDDEN + k0 + gcol, As  + r * BK + scol);
            GLDS(Wg + (size_t)(n0 + r) * HIDDEN + k0 + gcol, Bgs + r * BK + scol);
            GLDS(Wu + (size_t)(n0 + r) * HIDDEN + k0 + gcol, Bus + r * BK + scol);
        }
        __syncthreads();
#pragma unroll
        for (int ks = 0; ks < 2; ++ks) {
            bf16x8 af[4], bg[4], bu[4];
            const int pofs = (((ks * 4 + lq) ^ swr)) << 3;
#pragma unroll
            for (int im = 0; im < 4; ++im)
                af[im] = *(const bf16x8*)(As + (wr * 64 + im * 16 + ln15) * BK + pofs);
#pragma unroll
            for (int in = 0; in < 4; ++in) {
                bg[in] = *(const bf16x8*)(Bgs + (wc * 64 + in * 16 + ln15) * BK + pofs);
                bu[in] = *(const bf16x8*)(Bus + (wc * 64 + in * 16 + ln15) * BK + pofs);
            }
#pragma unroll
            for (int im = 0; im < 4; ++im)
#pragma unroll
                for (int in = 0; in < 4; ++in) {
                    accg[im][in] = __builtin_amdgcn_mfma_f32_16x16x32_bf16(af[im], bg[in], accg[im][in], 0, 0, 0);
                    accu[im][in] = __builtin_amdgcn_mfma_f32_16x16x32_bf16(af[im], bu[in], accu[im][in], 0, 0, 0);
                }
        }
    }

#pragma unroll
    for (int im = 0; im < 4; ++im)
#pragma unroll
        for (int in = 0; in < 4; ++in) {
            const int row = m0 + wr * 64 + im * 16 + lq * 4;
            const int col = n0 + wc * 64 + in * 16 + ln15;
#pragma unroll
            for (int r = 0; r < 4; ++r) {
                float g = accg[im][in][r];
                float u = accu[im][in][r];
                float h = g * (1.0f / (1.0f + __expf(-g))) * u;
                H[(size_t)(row + r) * INTER + col] = f2bf(h);
            }
        }
}

// ---------------- GEMM2: Out = H Wd^T, fp32 out ----------------
// Counted-vmcnt double-buffered pipeline @ 2 blocks/CU (R11); group 2 (R12).
__global__ __launch_bounds__(256, 2) void gemm2_kernel(const unsigned short* __restrict__ Hin,
                                                       const unsigned short* __restrict__ Wd,
                                                       float* __restrict__ Out) {
    __shared__ unsigned short As[2][BM * BK];   // 32 KB
    __shared__ unsigned short Bs[2][BN * BK];   // 32 KB

    const int tid  = threadIdx.x;
    const int lane = tid & 63;
    const int wave = tid >> 6;
    int mb, nb;
    decode_block(blockIdx.x, TOKENS / BM, HIDDEN / BN, 2, &mb, &nb);
    const int m0 = mb * BM;
    const int n0 = nb * BN;

    const int srow = tid >> 3;
    const int scol = (tid & 7) << 3;
    const int gcol = (((tid & 7) ^ (srow & 7))) << 3;

    const int wr = wave >> 1;
    const int wc = wave & 1;
    const int ln15 = lane & 15;
    const int lq = lane >> 4;
    const int swr = ln15 & 7;

    f32x4 acc[4][4];
    const f32x4 z = {0.f, 0.f, 0.f, 0.f};
    for (int i = 0; i < 4; ++i)
        for (int j = 0; j < 4; ++j) acc[i][j] = z;

    // 8 GLDS per thread per K-tile: A x4, B x4
#define STAGE2(buf, kt) do {                                                        \
        const int k0_ = (kt) * BK;                                                  \
        _Pragma("unroll")                                                           \
        for (int i_ = 0; i_ < 4; ++i_) {                                            \
            const int r_ = i_ * 32 + srow;                                          \
            GLDS(Hin + (size_t)(m0 + r_) * INTER + k0_ + gcol,                      \
                 &As[buf][r_ * BK + scol]);                                         \
        }                                                                           \
        _Pragma("unroll")                                                           \
        for (int i_ = 0; i_ < 4; ++i_) {                                            \
            const int r_ = i_ * 32 + srow;                                          \
            GLDS(Wd + (size_t)(n0 + r_) * INTER + k0_ + gcol,                       \
                 &Bs[buf][r_ * BK + scol]);                                         \
        }                                                                           \
    } while (0)

    STAGE2(0, 0);
    STAGE2(1, 1);                       // 16 loads in flight per thread

    for (int t = 0; t < NT2; ++t) {
        const int cur = t & 1;
        if (t + 1 < NT2) {
            asm volatile("s_waitcnt vmcnt(8)" ::: "memory");
        } else {
            asm volatile("s_waitcnt vmcnt(0)" ::: "memory");
        }
        __builtin_amdgcn_s_barrier();   // all waves' tile-t data visible

        // ---- ks = 0 ----
        bf16x8 a0[4], b0[4];
        {
            const int pofs = ((lq ^ swr)) << 3;
#pragma unroll
            for (int im = 0; im < 4; ++im)
                a0[im] = *(const bf16x8*)(&As[cur][(wr * 64 + im * 16 + ln15) * BK + pofs]);
#pragma unroll
            for (int in = 0; in < 4; ++in)
                b0[in] = *(const bf16x8*)(&Bs[cur][(wc * 64 + in * 16 + ln15) * BK + pofs]);
        }
#pragma unroll
        for (int im = 0; im < 4; ++im)
#pragma unroll
            for (int in = 0; in < 4; ++in)
                acc[im][in] = __builtin_amdgcn_mfma_f32_16x16x32_bf16(a0[im], b0[in], acc[im][in], 0, 0, 0);

        // ---- ks = 1 ----
        bf16x8 a1[4], b1[4];
        {
            const int pofs = (((4 + lq) ^ swr)) << 3;
#pragma unroll
            for (int im = 0; im < 4; ++im)
                a1[im] = *(const bf16x8*)(&As[cur][(wr * 64 + im * 16 + ln15) * BK + pofs]);
#pragma unroll
            for (int in = 0; in < 4; ++in)
                b1[in] = *(const bf16x8*)(&Bs[cur][(wc * 64 + in * 16 + ln15) * BK + pofs]);
        }
        asm volatile("s_waitcnt lgkmcnt(0)" ::: "memory");  // my LDS reads done
        __builtin_amdgcn_s_barrier();                        // everyone's reads done
        if (t + 2 < NT2) STAGE2(cur, t + 2);  // overwrite freed buf under ks1 MFMAs
#pragma unroll
        for (int im = 0; im < 4; ++im)
#pragma unroll
            for (int in = 0; in < 4; ++in)
                acc[im][in] = __builtin_amdgcn_mfma_f32_16x16x32_bf16(a1[im], b1[in], acc[im][in], 0, 0, 0);
    }
#undef STAGE2

#pragma unroll
    for (int im = 0; im < 4; ++im)
#pragma unroll
        for (int in = 0; in < 4; ++in) {
            const int row = m0 + wr * 64 + im * 16 + lq * 4;
            const int col = n0 + wc * 64 + in * 16 + ln15;
#pragma unroll
            for (int r = 0; r < 4; ++r)
                Out[(size_t)(row + r) * HIDDEN + col] = acc[im][in][r];
        }
}

extern "C" void kernel_launch(void* const* d_in, const int* in_sizes, int n_in,
                              void* d_out, int out_size, void* d_ws, size_t ws_size,
                              hipStream_t stream) {
    (void)in_sizes; (void)n_in; (void)out_size; (void)ws_size;

    const float* x   = (const float*)d_in[0];
    const float* cbg = (const float*)d_in[1];
    const int*   ig  = (const int*)d_in[2];
    const float* sg  = (const float*)d_in[3];
    const float* cbu = (const float*)d_in[4];
    const int*   iu  = (const int*)d_in[5];
    const float* su  = (const float*)d_in[6];
    const float* cbd = (const float*)d_in[7];
    const int*   idn = (const int*)d_in[8];
    const float* sd  = (const float*)d_in[9];
    float* out = (float*)d_out;

    char* p = (char*)d_ws;
    unsigned short* Xb = (unsigned short*)p; p += (size_t)TOKENS * HIDDEN * 2;
    unsigned short* Wg = (unsigned short*)p; p += (size_t)INTER * HIDDEN * 2;
    unsigned short* Wu = (unsigned short*)p; p += (size_t)INTER * HIDDEN * 2;
    unsigned short* Wd = (unsigned short*)p; p += (size_t)HIDDEN * INTER * 2;
    unsigned short* H  = (unsigned short*)p; p += (size_t)TOKENS * INTER * 2;

    cast_kernel<<<dim3(TOKENS * HIDDEN / 8 / 512), dim3(512), 0, stream>>>(x, Xb);
    prep_kernel<<<dim3(352), dim3(512), 0, stream>>>(ig, cbg, sg, Wg, iu, cbu, su, Wu);

    gemm1_kernel<<<dim3(G1B + WDB), dim3(256), 0, stream>>>(Xb, Wg, Wu, H,
                                                            idn, cbd, sd, Wd);
    gemm2_kernel<<<dim3((TOKENS / BM) * (HIDDEN / BN)), dim3(256), 0, stream>>>(H, Wd, out);
}

// Round 8
// 369.017 us; speedup vs baseline: 1.0163x; 1.0163x over previous
//
#include <hip/hip_runtime.h>

#define HIDDEN 2048
#define INTER  5632
#define TOKENS 4096

#define BM 128
#define BN 128
#define BK 64
#define NT2 (INTER / BK)   // 88 K-tiles for gemm2

#define G1B ((TOKENS / BM) * (INTER / BN))   // 1408 gemm1 blocks
#define WDB 352                               // Wd-dequant trailing blocks

using bf16x8 = __attribute__((ext_vector_type(8))) __bf16;
using f32x4  = __attribute__((ext_vector_type(4))) float;

__device__ __forceinline__ unsigned short f2bf(float f) {
    unsigned int u = __float_as_uint(f);
    u += 0x7FFFu + ((u >> 16) & 1u);
    return (unsigned short)(u >> 16);
}

#define GLDS(gptr, lptr) \
    __builtin_amdgcn_global_load_lds((__attribute__((address_space(1))) void*)(gptr), \
                                     (__attribute__((address_space(3))) void*)(lptr), 16, 0, 0)

// Journal:
// R2: XOR-swizzle conflict-free w/ 16x16 frags. R5: group-raster FETCH -30%.
// R8: 32x32 frags 4-way bank-conflict at BK=64 — 16x16 only. R3: (256,3)
// gemm1 spills. R4: BK=32 dbuf regressed. R6: barrier-free glds UNSAFE.
// R9 FAILED: 8-phase port (1 blk/CU): 48->31%, 176->252us.
// R10 FAILED: min-2-phase 256x128 @ 1 blk/CU: 36%, 219us (128KB LDS kills
//   2-blk de-phasing). R11: gemm1=R0 verified; gemm2 counted-vmcnt NEUTRAL.
// R12 DIAG: gemm1 2-way split +45us -> dispatch-round tails / launch count
//   are first-order. prep,gemm2 each <109, sum ~188 incl gaps.
// R13 FAILED: L2-gather prep +12us (lane-divergent gather >> LDS gather).
// R14: ILP-16 idx preload ~0 vs R7-prep (prep not idx-latency-bound).
// R15 MIXED: (a) Wd-merge into gemm1 tail = +4.1us only (WIN, kept);
//   (b) cast split + 352-block prep = +8.9us REST regression (single-round
//   prep loses mixed dequant/cast overlap; +1 launch gap) -> REVERTED.
// R16 (this round): recomposition. gemm1 keeps Wd trailing blocks (R15a);
//   prep = 352 Wg/Wu dequant + 2048 cast blocks in ONE launch (R6-style
//   mixing); 3 launches total. No inner loop touched.
// ---------------------------------------------------------------------

// ---------------- prep: dequant Wg/Wu (LDS codebook) + cast x ----------------
__global__ __launch_bounds__(512) void prep_kernel(
        const float* __restrict__ x, unsigned short* __restrict__ xb,
        const int* __restrict__ ig, const float* __restrict__ cbg,
        const float* __restrict__ sg, unsigned short* __restrict__ wg,
        const int* __restrict__ iu, const float* __restrict__ cbu,
        const float* __restrict__ su, unsigned short* __restrict__ wu) {
    __shared__ unsigned short cbl[4096 * 8];   // 64 KB bf16 codebook
    const int b = blockIdx.x;
    const int tid = threadIdx.x;

    if (b >= 352) {                            // ---- cast x ----
        int t = (b - 352) * 512 + tid;
        const float4* x4 = (const float4*)x;
        float4 a = x4[2 * t];
        float4 c = x4[2 * t + 1];
        uint4 o;
        o.x = f2bf(a.x) | ((unsigned int)f2bf(a.y) << 16);
        o.y = f2bf(a.z) | ((unsigned int)f2bf(a.w) << 16);
        o.z = f2bf(c.x) | ((unsigned int)f2bf(c.y) << 16);
        o.w = f2bf(c.z) | ((unsigned int)f2bf(c.w) << 16);
        ((uint4*)xb)[t] = o;
        return;
    }

    const int mat = b / 176;
    const int bl  = b % 176;
    const int* idx; const float* cb; const float* scale; unsigned short* w;
    if (mat == 0) { idx = ig; cb = cbg; scale = sg; w = wg; }
    else          { idx = iu; cb = cbu; scale = su; w = wu; }
    const int ncol8 = HIDDEN / 8;

    const size_t base = (size_t)bl * 8192;

    // batched idx/scale preload (R14): HBM chains hide under staging
    int   ids[16];
    float ss[16];
#pragma unroll
    for (int i = 0; i < 16; ++i) {
        size_t t = base + i * 512 + tid;
        ids[i] = idx[t];
        ss[i]  = scale[t / ncol8];
    }

#pragma unroll
    for (int i = 0; i < 8; ++i) {
        int r = i * 512 + tid;
        const float4* c4 = (const float4*)(cb + ((size_t)r << 3));
        float4 a = c4[0];
        float4 c = c4[1];
        uint4 o;
        o.x = f2bf(a.x) | ((unsigned int)f2bf(a.y) << 16);
        o.y = f2bf(a.z) | ((unsigned int)f2bf(a.w) << 16);
        o.z = f2bf(c.x) | ((unsigned int)f2bf(c.y) << 16);
        o.w = f2bf(c.z) | ((unsigned int)f2bf(c.w) << 16);
        ((uint4*)cbl)[r] = o;
    }
    __syncthreads();

#pragma unroll
    for (int i = 0; i < 16; ++i) {
        size_t t = base + i * 512 + tid;
        const unsigned short* cw = cbl + ((unsigned)ids[i] << 3);
        uint4 cv = *(const uint4*)cw;
        float s = ss[i];
        unsigned int ww[4];
#pragma unroll
        for (int j = 0; j < 4; ++j) {
            unsigned int pair = (&cv.x)[j];
            float lo = __uint_as_float(pair << 16) * s;
            float hi = __uint_as_float(pair & 0xFFFF0000u) * s;
            ww[j] = f2bf(lo) | ((unsigned int)f2bf(hi) << 16);
        }
        uint4 o = {ww[0], ww[1], ww[2], ww[3]};
        ((uint4*)w)[t] = o;
    }
}

__device__ __forceinline__ void decode_block(int bid, int nblocks_m, int nblocks_n,
                                             int gN, int* mb, int* nb) {
    int gw = nblocks_m * gN;
    int group = bid / gw;
    int inb = bid % gw;
    int gn = group * gN;
    int width = (nblocks_n - gn < gN) ? (nblocks_n - gn) : gN;
    *mb = inb / width;
    *nb = gn + inb % width;
}

// ---------------- GEMM1 + trailing Wd-dequant blocks ----------------
// bid < G1B: R0-exact gemm1 (128x128, 2-barrier, verified 173.5us/49%).
// bid >= G1B: Wd dequant (256 thr, 16 codes/thr) — consumed only by gemm2,
// so stream-order makes this race-free; fills gemm1's tail round.
// R15 measured: absorbing Wd here costs only +4.1us on gemm1.
__global__ __launch_bounds__(256, 2) void gemm1_kernel(const unsigned short* __restrict__ X,
                                                       const unsigned short* __restrict__ Wg,
                                                       const unsigned short* __restrict__ Wu,
                                                       unsigned short* __restrict__ H,
                                                       const int* __restrict__ idn,
                                                       const float* __restrict__ cbd,
                                                       const float* __restrict__ sd,
                                                       unsigned short* __restrict__ Wd) {
    __shared__ unsigned short smem[32768];   // 64 KB: tiles (48KB) | codebook (64KB)

    const int tid  = threadIdx.x;

    if (blockIdx.x >= G1B) {
        // ---------- Wd dequant ----------
        const int bl = blockIdx.x - G1B;          // 0..351
        const size_t base = (size_t)bl * 4096;    // 352*4096 = 1.44M codes
        const int ncol8 = INTER / 8;              // 704

        int   ids[16];
        float ss[16];
#pragma unroll
        for (int i = 0; i < 16; ++i) {
            size_t t = base + i * 256 + tid;
            ids[i] = idn[t];
            ss[i]  = sd[t / ncol8];
        }
#pragma unroll
        for (int i = 0; i < 16; ++i) {            // 4096 entries / 256 thr
            int r = i * 256 + tid;
            const float4* c4 = (const float4*)(cbd + ((size_t)r << 3));
            float4 a = c4[0];
            float4 c = c4[1];
            uint4 o;
            o.x = f2bf(a.x) | ((unsigned int)f2bf(a.y) << 16);
            o.y = f2bf(a.z) | ((unsigned int)f2bf(a.w) << 16);
            o.z = f2bf(c.x) | ((unsigned int)f2bf(c.y) << 16);
            o.w = f2bf(c.z) | ((unsigned int)f2bf(c.w) << 16);
            ((uint4*)smem)[r] = o;
        }
        __syncthreads();
#pragma unroll
        for (int i = 0; i < 16; ++i) {
            size_t t = base + i * 256 + tid;
            const unsigned short* cw = smem + ((unsigned)ids[i] << 3);
            uint4 cv = *(const uint4*)cw;
            float s = ss[i];
            unsigned int ww[4];
#pragma unroll
            for (int j = 0; j < 4; ++j) {
                unsigned int pair = (&cv.x)[j];
                float lo = __uint_as_float(pair << 16) * s;
                float hi = __uint_as_float(pair & 0xFFFF0000u) * s;
                ww[j] = f2bf(lo) | ((unsigned int)f2bf(hi) << 16);
            }
            uint4 o = {ww[0], ww[1], ww[2], ww[3]};
            ((uint4*)Wd)[t] = o;
        }
        return;
    }

    // ---------- gemm1 (R0-exact body, smem-aliased tiles) ----------
    unsigned short* As  = smem;            // 16 KB
    unsigned short* Bgs = smem + 8192;     // 16 KB
    unsigned short* Bus = smem + 16384;    // 16 KB

    const int lane = tid & 63;
    const int wave = tid >> 6;
    int mb, nb;
    decode_block(blockIdx.x, TOKENS / BM, INTER / BN, 4, &mb, &nb);
    const int m0 = mb * BM;
    const int n0 = nb * BN;

    const int srow = tid >> 3;
    const int scol = (tid & 7) << 3;
    const int gcol = (((tid & 7) ^ (srow & 7))) << 3;

    const int wr = wave >> 1;
    const int wc = wave & 1;
    const int ln15 = lane & 15;
    const int lq = lane >> 4;
    const int swr = ln15 & 7;

    f32x4 accg[4][4], accu[4][4];
    const f32x4 z = {0.f, 0.f, 0.f, 0.f};
    for (int i = 0; i < 4; ++i)
        for (int j = 0; j < 4; ++j) { accg[i][j] = z; accu[i][j] = z; }

    for (int kt = 0; kt < HIDDEN / BK; ++kt) {
        const int k0 = kt * BK;
        __syncthreads();
#pragma unroll
        for (int i = 0; i < 4; ++i) {
            const int r = i * 32 + srow;
            GLDS(X  + (size_t)(m0 + r) * HIDDEN + k0 + gcol, As  + r * BK + scol);
            GLDS(Wg + (size_t)(n0 + r) * HIDDEN + k0 + gcol, Bgs + r * BK + scol);
            GLDS(Wu + (size_t)(n0 + r) * HIDDEN + k0 + gcol, Bus + r * BK + scol);
        }
        __syncthreads();
#pragma unroll
        for (int ks = 0; ks < 2; ++ks) {
            bf16x8 af[4], bg[4], bu[4];
            const int pofs = (((ks * 4 + lq) ^ swr)) << 3;
#pragma unroll
            for (int im = 0; im < 4; ++im)
                af[im] = *(const bf16x8*)(As + (wr * 64 + im * 16 + ln15) * BK + pofs);
#pragma unroll
            for (int in = 0; in < 4; ++in) {
                bg[in] = *(const bf16x8*)(Bgs + (wc * 64 + in * 16 + ln15) * BK + pofs);
                bu[in] = *(const bf16x8*)(Bus + (wc * 64 + in * 16 + ln15) * BK + pofs);
            }
#pragma unroll
            for (int im = 0; im < 4; ++im)
#pragma unroll
                for (int in = 0; in < 4; ++in) {
                    accg[im][in] = __builtin_amdgcn_mfma_f32_16x16x32_bf16(af[im], bg[in], accg[im][in], 0, 0, 0);
                    accu[im][in] = __builtin_amdgcn_mfma_f32_16x16x32_bf16(af[im], bu[in], accu[im][in], 0, 0, 0);
                }
        }
    }

#pragma unroll
    for (int im = 0; im < 4; ++im)
#pragma unroll
        for (int in = 0; in < 4; ++in) {
            const int row = m0 + wr * 64 + im * 16 + lq * 4;
            const int col = n0 + wc * 64 + in * 16 + ln15;
#pragma unroll
            for (int r = 0; r < 4; ++r) {
                float g = accg[im][in][r];
                float u = accu[im][in][r];
                float h = g * (1.0f / (1.0f + __expf(-g))) * u;
                H[(size_t)(row + r) * INTER + col] = f2bf(h);
            }
        }
}

// ---------------- GEMM2: Out = H Wd^T, fp32 out ----------------
// Counted-vmcnt double-buffered pipeline @ 2 blocks/CU (R11); group 2 (R12).
__global__ __launch_bounds__(256, 2) void gemm2_kernel(const unsigned short* __restrict__ Hin,
                                                       const unsigned short* __restrict__ Wd,
                                                       float* __restrict__ Out) {
    __shared__ unsigned short As[2][BM * BK];   // 32 KB
    __shared__ unsigned short Bs[2][BN * BK];   // 32 KB

    const int tid  = threadIdx.x;
    const int lane = tid & 63;
    const int wave = tid >> 6;
    int mb, nb;
    decode_block(blockIdx.x, TOKENS / BM, HIDDEN / BN, 2, &mb, &nb);
    const int m0 = mb * BM;
    const int n0 = nb * BN;

    const int srow = tid >> 3;
    const int scol = (tid & 7) << 3;
    const int gcol = (((tid & 7) ^ (srow & 7))) << 3;

    const int wr = wave >> 1;
    const int wc = wave & 1;
    const int ln15 = lane & 15;
    const int lq = lane >> 4;
    const int swr = ln15 & 7;

    f32x4 acc[4][4];
    const f32x4 z = {0.f, 0.f, 0.f, 0.f};
    for (int i = 0; i < 4; ++i)
        for (int j = 0; j < 4; ++j) acc[i][j] = z;

    // 8 GLDS per thread per K-tile: A x4, B x4
#define STAGE2(buf, kt) do {                                                        \
        const int k0_ = (kt) * BK;                                                  \
        _Pragma("unroll")                                                           \
        for (int i_ = 0; i_ < 4; ++i_) {                                            \
            const int r_ = i_ * 32 + srow;                                          \
            GLDS(Hin + (size_t)(m0 + r_) * INTER + k0_ + gcol,                      \
                 &As[buf][r_ * BK + scol]);                                         \
        }                                                                           \
        _Pragma("unroll")                                                           \
        for (int i_ = 0; i_ < 4; ++i_) {                                            \
            const int r_ = i_ * 32 + srow;                                          \
            GLDS(Wd + (size_t)(n0 + r_) * INTER + k0_ + gcol,                       \
                 &Bs[buf][r_ * BK + scol]);                                         \
        }                                                                           \
    } while (0)

    STAGE2(0, 0);
    STAGE2(1, 1);                       // 16 loads in flight per thread

    for (int t = 0; t < NT2; ++t) {
        const int cur = t & 1;
        if (t + 1 < NT2) {
            asm volatile("s_waitcnt vmcnt(8)" ::: "memory");
        } else {
            asm volatile("s_waitcnt vmcnt(0)" ::: "memory");
        }
        __builtin_amdgcn_s_barrier();   // all waves' tile-t data visible

        // ---- ks = 0 ----
        bf16x8 a0[4], b0[4];
        {
            const int pofs = ((lq ^ swr)) << 3;
#pragma unroll
            for (int im = 0; im < 4; ++im)
                a0[im] = *(const bf16x8*)(&As[cur][(wr * 64 + im * 16 + ln15) * BK + pofs]);
#pragma unroll
            for (int in = 0; in < 4; ++in)
                b0[in] = *(const bf16x8*)(&Bs[cur][(wc * 64 + in * 16 + ln15) * BK + pofs]);
        }
#pragma unroll
        for (int im = 0; im < 4; ++im)
#pragma unroll
            for (int in = 0; in < 4; ++in)
                acc[im][in] = __builtin_amdgcn_mfma_f32_16x16x32_bf16(a0[im], b0[in], acc[im][in], 0, 0, 0);

        // ---- ks = 1 ----
        bf16x8 a1[4], b1[4];
        {
            const int pofs = (((4 + lq) ^ swr)) << 3;
#pragma unroll
            for (int im = 0; im < 4; ++im)
                a1[im] = *(const bf16x8*)(&As[cur][(wr * 64 + im * 16 + ln15) * BK + pofs]);
#pragma unroll
            for (int in = 0; in < 4; ++in)
                b1[in] = *(const bf16x8*)(&Bs[cur][(wc * 64 + in * 16 + ln15) * BK + pofs]);
        }
        asm volatile("s_waitcnt lgkmcnt(0)" ::: "memory");  // my LDS reads done
        __builtin_amdgcn_s_barrier();                        // everyone's reads done
        if (t + 2 < NT2) STAGE2(cur, t + 2);  // overwrite freed buf under ks1 MFMAs
#pragma unroll
        for (int im = 0; im < 4; ++im)
#pragma unroll
            for (int in = 0; in < 4; ++in)
                acc[im][in] = __builtin_amdgcn_mfma_f32_16x16x32_bf16(a1[im], b1[in], acc[im][in], 0, 0, 0);
    }
#undef STAGE2

#pragma unroll
    for (int im = 0; im < 4; ++im)
#pragma unroll
        for (int in = 0; in < 4; ++in) {
            const int row = m0 + wr * 64 + im * 16 + lq * 4;
            const int col = n0 + wc * 64 + in * 16 + ln15;
#pragma unroll
            for (int r = 0; r < 4; ++r)
                Out[(size_t)(row + r) * HIDDEN + col] = acc[im][in][r];
        }
}

extern "C" void kernel_launch(void* const* d_in, const int* in_sizes, int n_in,
                              void* d_out, int out_size, void* d_ws, size_t ws_size,
                              hipStream_t stream) {
    (void)in_sizes; (void)n_in; (void)out_size; (void)ws_size;

    const float* x   = (const float*)d_in[0];
    const float* cbg = (const float*)d_in[1];
    const int*   ig  = (const int*)d_in[2];
    const float* sg  = (const float*)d_in[3];
    const float* cbu = (const float*)d_in[4];
    const int*   iu  = (const int*)d_in[5];
    const float* su  = (const float*)d_in[6];
    const float* cbd = (const float*)d_in[7];
    const int*   idn = (const int*)d_in[8];
    const float* sd  = (const float*)d_in[9];
    float* out = (float*)d_out;

    char* p = (char*)d_ws;
    unsigned short* Xb = (unsigned short*)p; p += (size_t)TOKENS * HIDDEN * 2;
    unsigned short* Wg = (unsigned short*)p; p += (size_t)INTER * HIDDEN * 2;
    unsigned short* Wu = (unsigned short*)p; p += (size_t)INTER * HIDDEN * 2;
    unsigned short* Wd = (unsigned short*)p; p += (size_t)HIDDEN * INTER * 2;
    unsigned short* H  = (unsigned short*)p; p += (size_t)TOKENS * INTER * 2;

    // prep: 352 Wg/Wu-dequant blocks + 2048 cast blocks, one launch (mixing
    // latency-bound dequant with BW-bound cast — R15b showed separating
    // them costs ~9us).
    prep_kernel<<<dim3(352 + 2048), dim3(512), 0, stream>>>(
        x, Xb, ig, cbg, sg, Wg, iu, cbu, su, Wu);

    // gemm1 + Wd dequant in trailing blocks (R15a: +4.1us only).
    gemm1_kernel<<<dim3(G1B + WDB), dim3(256), 0, stream>>>(Xb, Wg, Wu, H,
                                                            idn, cbd, sd, Wd);
    gemm2_kernel<<<dim3((TOKENS / BM) * (HIDDEN / BN)), dim3(256), 0, stream>>>(H, Wd, out);
}

// Round 9
// 366.269 us; speedup vs baseline: 1.0239x; 1.0075x over previous
//
#include <hip/hip_runtime.h>

#define HIDDEN 2048
#define INTER  5632
#define TOKENS 4096

#define BM 128
#define BN 128
#define BK 64
#define NT2 (INTER / BK)   // 88 K-tiles for gemm2

using bf16x8 = __attribute__((ext_vector_type(8))) __bf16;
using f32x4  = __attribute__((ext_vector_type(4))) float;

__device__ __forceinline__ unsigned short f2bf(float f) {
    unsigned int u = __float_as_uint(f);
    u += 0x7FFFu + ((u >> 16) & 1u);
    return (unsigned short)(u >> 16);
}

#define GLDS(gptr, lptr) \
    __builtin_amdgcn_global_load_lds((__attribute__((address_space(1))) void*)(gptr), \
                                     (__attribute__((address_space(3))) void*)(lptr), 16, 0, 0)

// Journal:
// R2: XOR-swizzle conflict-free w/ 16x16 frags. R5: group-raster FETCH -30%.
// R8: 32x32 frags 4-way bank-conflict at BK=64 — 16x16 only. R3: (256,3)
// gemm1 spills. R4: BK=32 dbuf regressed. R6: barrier-free glds UNSAFE.
// R9 FAILED: 8-phase port (1 blk/CU): 48->31%, 176->252us.
// R10 FAILED: min-2-phase 256x128 @ 1 blk/CU: 36%, 219us (128KB LDS kills
//   2-blk de-phasing). R11: gemm1=R0 verified; gemm2 counted-vmcnt NEUTRAL.
// R12 DIAG: gemm1 2-way split +45us -> dispatch-round tails / launch count
//   are first-order. prep,gemm2 each <109, sum ~188 incl gaps.
// R13 FAILED: L2-gather prep +12us (lane-divergent gather >> LDS gather).
// R14: ILP-16 idx preload ~0 (prep not idx-chain-latency-bound).
// R15 MIXED: Wd->gemm1 tail +4.1us on gemm1; cast-split prep +8.9us rest.
// R16 FAILED: recomposition (Wd in gemm1 tail + mixed prep-minus-Wd) =
//   369. Rest unchanged when Wd removed from prep => Wd was FREE under
//   the cast blocks' BW-bound overlap. Lesson: work overlapping a
//   BW-bound co-resident phase has zero marginal cost — don't relocate.
//   Best verified: R6 structure @ 362.0.
// R17 (this round): REVERT to R6 exact; single rider in prep dequant:
//   process 4 CONSECUTIVE codes/step -> int4 idx loads (16->4), scale
//   lookups 16->4 (4-aligned quads never straddle a scale row), stores
//   64B-contiguous/lane. Tests the issue-count hypothesis (the one class
//   not yet tested on prep). gemm1/gemm2 byte-identical to R6.
// ---------------------------------------------------------------------

// ---------------- prep: dequant (LDS codebook) + cast x ----------------
__global__ __launch_bounds__(512) void prep_kernel(
        const float* __restrict__ x, unsigned short* __restrict__ xb,
        const int* __restrict__ ig, const float* __restrict__ cbg,
        const float* __restrict__ sg, unsigned short* __restrict__ wg,
        const int* __restrict__ iu, const float* __restrict__ cbu,
        const float* __restrict__ su, unsigned short* __restrict__ wu,
        const int* __restrict__ idn, const float* __restrict__ cbd,
        const float* __restrict__ sd, unsigned short* __restrict__ wd) {
    __shared__ unsigned short cbl[4096 * 8];   // 64 KB bf16 codebook
    const int b = blockIdx.x;
    const int tid = threadIdx.x;

    if (b >= 528) {                            // ---- cast x ----
        int t = (b - 528) * 512 + tid;
        const float4* x4 = (const float4*)x;
        float4 a = x4[2 * t];
        float4 c = x4[2 * t + 1];
        uint4 o;
        o.x = f2bf(a.x) | ((unsigned int)f2bf(a.y) << 16);
        o.y = f2bf(a.z) | ((unsigned int)f2bf(a.w) << 16);
        o.z = f2bf(c.x) | ((unsigned int)f2bf(c.y) << 16);
        o.w = f2bf(c.z) | ((unsigned int)f2bf(c.w) << 16);
        ((uint4*)xb)[t] = o;
        return;
    }

    const int mat = b / 176;
    const int bl  = b % 176;
    const int* idx; const float* cb; const float* scale; unsigned short* w; int ncol8;
    if (mat == 0)      { idx = ig;  cb = cbg; scale = sg; w = wg; ncol8 = HIDDEN / 8; }
    else if (mat == 1) { idx = iu;  cb = cbu; scale = su; w = wu; ncol8 = HIDDEN / 8; }
    else               { idx = idn; cb = cbd; scale = sd; w = wd; ncol8 = INTER / 8; }

    const size_t base = (size_t)bl * 8192;

    // R17: quad-code layout. 4 int4 idx loads + 4 scale loads per thread
    // (was 16 + 16). t0 is 4-aligned and ncol8 % 4 == 0 -> a quad never
    // straddles a scale row. Preloaded before staging (R14 hiding).
    int4  iv[4];
    float ss[4];
#pragma unroll
    for (int c = 0; c < 4; ++c) {
        size_t t0 = base + c * 2048 + (size_t)tid * 4;
        iv[c] = ((const int4*)idx)[t0 >> 2];
        ss[c] = scale[t0 / ncol8];
    }

    // stage fp32 codebook -> bf16 LDS
#pragma unroll
    for (int i = 0; i < 8; ++i) {
        int r = i * 512 + tid;
        const float4* c4 = (const float4*)(cb + ((size_t)r << 3));
        float4 a = c4[0];
        float4 c = c4[1];
        uint4 o;
        o.x = f2bf(a.x) | ((unsigned int)f2bf(a.y) << 16);
        o.y = f2bf(a.z) | ((unsigned int)f2bf(a.w) << 16);
        o.z = f2bf(c.x) | ((unsigned int)f2bf(c.y) << 16);
        o.w = f2bf(c.z) | ((unsigned int)f2bf(c.w) << 16);
        ((uint4*)cbl)[r] = o;
    }
    __syncthreads();

    // 16 gather->scale->store chains; stores 64B contiguous per lane
#pragma unroll
    for (int c = 0; c < 4; ++c) {
        size_t t0 = base + c * 2048 + (size_t)tid * 4;
        float s = ss[c];
#pragma unroll
        for (int k = 0; k < 4; ++k) {
            int id = (&iv[c].x)[k];
            const unsigned short* cw = cbl + ((unsigned)id << 3);
            uint4 cv = *(const uint4*)cw;
            unsigned int ww[4];
#pragma unroll
            for (int j = 0; j < 4; ++j) {
                unsigned int pair = (&cv.x)[j];
                float lo = __uint_as_float(pair << 16) * s;
                float hi = __uint_as_float(pair & 0xFFFF0000u) * s;
                ww[j] = f2bf(lo) | ((unsigned int)f2bf(hi) << 16);
            }
            uint4 o = {ww[0], ww[1], ww[2], ww[3]};
            ((uint4*)w)[t0 + k] = o;
        }
    }
}

__device__ __forceinline__ void decode_block(int bid, int nblocks_m, int nblocks_n,
                                             int gN, int* mb, int* nb) {
    int gw = nblocks_m * gN;
    int group = bid / gw;
    int inb = bid % gw;
    int gn = group * gN;
    int width = (nblocks_n - gn < gN) ? (nblocks_n - gn) : gN;
    *mb = inb / width;
    *nb = gn + inb % width;
}

// ---------------- GEMM1: H = silu(X Wg^T) * (X Wu^T), bf16 out ----------------
// R0-exact verified kernel: 128x128, 256 thr, (256,2), single-buf 2-barrier.
__global__ __launch_bounds__(256, 2) void gemm1_kernel(const unsigned short* __restrict__ X,
                                                       const unsigned short* __restrict__ Wg,
                                                       const unsigned short* __restrict__ Wu,
                                                       unsigned short* __restrict__ H) {
    __shared__ unsigned short As[BM * BK];
    __shared__ unsigned short Bgs[BN * BK];
    __shared__ unsigned short Bus[BN * BK];

    const int tid  = threadIdx.x;
    const int lane = tid & 63;
    const int wave = tid >> 6;
    int mb, nb;
    decode_block(blockIdx.x, TOKENS / BM, INTER / BN, 4, &mb, &nb);
    const int m0 = mb * BM;
    const int n0 = nb * BN;

    const int srow = tid >> 3;
    const int scol = (tid & 7) << 3;
    const int gcol = (((tid & 7) ^ (srow & 7))) << 3;

    const int wr = wave >> 1;
    const int wc = wave & 1;
    const int ln15 = lane & 15;
    const int lq = lane >> 4;
    const int swr = ln15 & 7;

    f32x4 accg[4][4], accu[4][4];
    const f32x4 z = {0.f, 0.f, 0.f, 0.f};
    for (int i = 0; i < 4; ++i)
        for (int j = 0; j < 4; ++j) { accg[i][j] = z; accu[i][j] = z; }

    for (int kt = 0; kt < HIDDEN / BK; ++kt) {
        const int k0 = kt * BK;
        __syncthreads();
#pragma unroll
        for (int i = 0; i < 4; ++i) {
            const int r = i * 32 + srow;
            GLDS(X  + (size_t)(m0 + r) * HIDDEN + k0 + gcol, As  + r * BK + scol);
            GLDS(Wg + (size_t)(n0 + r) * HIDDEN + k0 + gcol, Bgs + r * BK + scol);
            GLDS(Wu + (size_t)(n0 + r) * HIDDEN + k0 + gcol, Bus + r * BK + scol);
        }
        __syncthreads();
#pragma unroll
        for (int ks = 0; ks < 2; ++ks) {
            bf16x8 af[4], bg[4], bu[4];
            const int pofs = (((ks * 4 + lq) ^ swr)) << 3;
#pragma unroll
            for (int im = 0; im < 4; ++im)
                af[im] = *(const bf16x8*)(As + (wr * 64 + im * 16 + ln15) * BK + pofs);
#pragma unroll
            for (int in = 0; in < 4; ++in) {
                bg[in] = *(const bf16x8*)(Bgs + (wc * 64 + in * 16 + ln15) * BK + pofs);
                bu[in] = *(const bf16x8*)(Bus + (wc * 64 + in * 16 + ln15) * BK + pofs);
            }
#pragma unroll
            for (int im = 0; im < 4; ++im)
#pragma unroll
                for (int in = 0; in < 4; ++in) {
                    accg[im][in] = __builtin_amdgcn_mfma_f32_16x16x32_bf16(af[im], bg[in], accg[im][in], 0, 0, 0);
                    accu[im][in] = __builtin_amdgcn_mfma_f32_16x16x32_bf16(af[im], bu[in], accu[im][in], 0, 0, 0);
                }
        }
    }

#pragma unroll
    for (int im = 0; im < 4; ++im)
#pragma unroll
        for (int in = 0; in < 4; ++in) {
            const int row = m0 + wr * 64 + im * 16 + lq * 4;
            const int col = n0 + wc * 64 + in * 16 + ln15;
#pragma unroll
            for (int r = 0; r < 4; ++r) {
                float g = accg[im][in][r];
                float u = accu[im][in][r];
                float h = g * (1.0f / (1.0f + __expf(-g))) * u;
                H[(size_t)(row + r) * INTER + col] = f2bf(h);
            }
        }
}

// ---------------- GEMM2: Out = H Wd^T, fp32 out ----------------
// Counted-vmcnt double-buffered pipeline @ 2 blocks/CU (R11); group 2 (R12).
__global__ __launch_bounds__(256, 2) void gemm2_kernel(const unsigned short* __restrict__ Hin,
                                                       const unsigned short* __restrict__ Wd,
                                                       float* __restrict__ Out) {
    __shared__ unsigned short As[2][BM * BK];   // 32 KB
    __shared__ unsigned short Bs[2][BN * BK];   // 32 KB

    const int tid  = threadIdx.x;
    const int lane = tid & 63;
    const int wave = tid >> 6;
    int mb, nb;
    decode_block(blockIdx.x, TOKENS / BM, HIDDEN / BN, 2, &mb, &nb);
    const int m0 = mb * BM;
    const int n0 = nb * BN;

    const int srow = tid >> 3;
    const int scol = (tid & 7) << 3;
    const int gcol = (((tid & 7) ^ (srow & 7))) << 3;

    const int wr = wave >> 1;
    const int wc = wave & 1;
    const int ln15 = lane & 15;
    const int lq = lane >> 4;
    const int swr = ln15 & 7;

    f32x4 acc[4][4];
    const f32x4 z = {0.f, 0.f, 0.f, 0.f};
    for (int i = 0; i < 4; ++i)
        for (int j = 0; j < 4; ++j) acc[i][j] = z;

    // 8 GLDS per thread per K-tile: A x4, B x4
#define STAGE2(buf, kt) do {                                                        \
        const int k0_ = (kt) * BK;                                                  \
        _Pragma("unroll")                                                           \
        for (int i_ = 0; i_ < 4; ++i_) {                                            \
            const int r_ = i_ * 32 + srow;                                          \
            GLDS(Hin + (size_t)(m0 + r_) * INTER + k0_ + gcol,                      \
                 &As[buf][r_ * BK + scol]);                                         \
        }                                                                           \
        _Pragma("unroll")                                                           \
        for (int i_ = 0; i_ < 4; ++i_) {                                            \
            const int r_ = i_ * 32 + srow;                                          \
            GLDS(Wd + (size_t)(n0 + r_) * INTER + k0_ + gcol,                       \
                 &Bs[buf][r_ * BK + scol]);                                         \
        }                                                                           \
    } while (0)

    STAGE2(0, 0);
    STAGE2(1, 1);                       // 16 loads in flight per thread

    for (int t = 0; t < NT2; ++t) {
        const int cur = t & 1;
        if (t + 1 < NT2) {
            asm volatile("s_waitcnt vmcnt(8)" ::: "memory");
        } else {
            asm volatile("s_waitcnt vmcnt(0)" ::: "memory");
        }
        __builtin_amdgcn_s_barrier();   // all waves' tile-t data visible

        // ---- ks = 0 ----
        bf16x8 a0[4], b0[4];
        {
            const int pofs = ((lq ^ swr)) << 3;
#pragma unroll
            for (int im = 0; im < 4; ++im)
                a0[im] = *(const bf16x8*)(&As[cur][(wr * 64 + im * 16 + ln15) * BK + pofs]);
#pragma unroll
            for (int in = 0; in < 4; ++in)
                b0[in] = *(const bf16x8*)(&Bs[cur][(wc * 64 + in * 16 + ln15) * BK + pofs]);
        }
#pragma unroll
        for (int im = 0; im < 4; ++im)
#pragma unroll
            for (int in = 0; in < 4; ++in)
                acc[im][in] = __builtin_amdgcn_mfma_f32_16x16x32_bf16(a0[im], b0[in], acc[im][in], 0, 0, 0);

        // ---- ks = 1 ----
        bf16x8 a1[4], b1[4];
        {
            const int pofs = (((4 + lq) ^ swr)) << 3;
#pragma unroll
            for (int im = 0; im < 4; ++im)
                a1[im] = *(const bf16x8*)(&As[cur][(wr * 64 + im * 16 + ln15) * BK + pofs]);
#pragma unroll
            for (int in = 0; in < 4; ++in)
                b1[in] = *(const bf16x8*)(&Bs[cur][(wc * 64 + in * 16 + ln15) * BK + pofs]);
        }
        asm volatile("s_waitcnt lgkmcnt(0)" ::: "memory");  // my LDS reads done
        __builtin_amdgcn_s_barrier();                        // everyone's reads done
        if (t + 2 < NT2) STAGE2(cur, t + 2);  // overwrite freed buf under ks1 MFMAs
#pragma unroll
        for (int im = 0; im < 4; ++im)
#pragma unroll
            for (int in = 0; in < 4; ++in)
                acc[im][in] = __builtin_amdgcn_mfma_f32_16x16x32_bf16(a1[im], b1[in], acc[im][in], 0, 0, 0);
    }
#undef STAGE2

#pragma unroll
    for (int im = 0; im < 4; ++im)
#pragma unroll
        for (int in = 0; in < 4; ++in) {
            const int row = m0 + wr * 64 + im * 16 + lq * 4;
            const int col = n0 + wc * 64 + in * 16 + ln15;
#pragma unroll
            for (int r = 0; r < 4; ++r)
                Out[(size_t)(row + r) * HIDDEN + col] = acc[im][in][r];
        }
}

extern "C" void kernel_launch(void* const* d_in, const int* in_sizes, int n_in,
                              void* d_out, int out_size, void* d_ws, size_t ws_size,
                              hipStream_t stream) {
    (void)in_sizes; (void)n_in; (void)out_size; (void)ws_size;

    const float* x   = (const float*)d_in[0];
    const float* cbg = (const float*)d_in[1];
    const int*   ig  = (const int*)d_in[2];
    const float* sg  = (const float*)d_in[3];
    const float* cbu = (const float*)d_in[4];
    const int*   iu  = (const int*)d_in[5];
    const float* su  = (const float*)d_in[6];
    const float* cbd = (const float*)d_in[7];
    const int*   idn = (const int*)d_in[8];
    const float* sd  = (const float*)d_in[9];
    float* out = (float*)d_out;

    char* p = (char*)d_ws;
    unsigned short* Xb = (unsigned short*)p; p += (size_t)TOKENS * HIDDEN * 2;
    unsigned short* Wg = (unsigned short*)p; p += (size_t)INTER * HIDDEN * 2;
    unsigned short* Wu = (unsigned short*)p; p += (size_t)INTER * HIDDEN * 2;
    unsigned short* Wd = (unsigned short*)p; p += (size_t)HIDDEN * INTER * 2;
    unsigned short* H  = (unsigned short*)p; p += (size_t)TOKENS * INTER * 2;

    prep_kernel<<<dim3(528 + 2048), dim3(512), 0, stream>>>(
        x, Xb, ig, cbg, sg, Wg, iu, cbu, su, Wu, idn, cbd, sd, Wd);

    gemm1_kernel<<<dim3((TOKENS / BM) * (INTER / BN)), dim3(256), 0, stream>>>(Xb, Wg, Wu, H);
    gemm2_kernel<<<dim3((TOKENS / BM) * (HIDDEN / BN)), dim3(256), 0, stream>>>(H, Wd, out);
}

// Round 10
// 365.503 us; speedup vs baseline: 1.0261x; 1.0021x over previous
//
#include <hip/hip_runtime.h>

#define HIDDEN 2048
#define INTER  5632
#define TOKENS 4096

#define BM 128
#define BN 128
#define BK 64
#define NT2 (INTER / BK)   // 88 K-tiles for gemm2

using bf16x8 = __attribute__((ext_vector_type(8))) __bf16;
using f32x4  = __attribute__((ext_vector_type(4))) float;

__device__ __forceinline__ unsigned short f2bf(float f) {
    unsigned int u = __float_as_uint(f);
    u += 0x7FFFu + ((u >> 16) & 1u);
    return (unsigned short)(u >> 16);
}

#define GLDS(gptr, lptr) \
    __builtin_amdgcn_global_load_lds((__attribute__((address_space(1))) void*)(gptr), \
                                     (__attribute__((address_space(3))) void*)(lptr), 16, 0, 0)

// Journal (final):
// R2: XOR-swizzle conflict-free w/ 16x16 frags. R5: group-raster FETCH -30%.
// R8: 32x32 frags 4-way bank-conflict at BK=64 — 16x16 only. R3: (256,3)
// gemm1 spills. R4: BK=32 dbuf regressed. R6: barrier-free glds UNSAFE.
// R9 FAILED: 8-phase port (1 blk/CU): 48->31%, 176->252us.
// R10 FAILED: min-2-phase 256x128 @ 1 blk/CU: 36%, 219us (128KB LDS kills
//   2-blk de-phasing). R11: gemm1=R0 verified; gemm2 counted-vmcnt NEUTRAL.
// R12 DIAG: gemm1 2-way split +45us -> dispatch-round tails / launch count
//   are first-order. prep,gemm2 each <109us, sum ~188 incl gaps.
// R13 FAILED: L2-gather prep +12us (lane-divergent gather >> LDS gather).
// R14: ILP-16 idx preload ~0 (prep not idx-chain-latency-bound). 362.0 =
//   best verified total.
// R15 MIXED: Wd->gemm1 tail +4.1us on gemm1; cast-split prep +8.9us rest.
// R16 FAILED: recomposition = 369. Wd was FREE under cast's BW-bound
//   overlap — work overlapping a BW-bound co-resident phase has zero
//   marginal cost; don't relocate it.
// R17 FAILED: quad-code prep (int4 idx, 4x fewer scale lookups, 64B/lane
//   stores) = +4us — issue-count hypothesis dead; likely lost wave-level
//   store coalescing of the stride-512 layout.
// R18 (final): revert to R6 byte-exact — the best verified composition.
//   Structural constraints at this plateau (362us, NOT a HW roofline):
//   - gemm1 49% MfmaUtil = 2-barrier vmcnt(0)-drain ceiling; the 8-phase
//     256^2 escape is geometry-hostile (352-block grid, 1.4-round tail at
//     its forced 1 blk/CU; measured -31%/-20% in R9/R10).
//   - prep+gemm2+gaps ~188us: each kernel <109us; 4 acceleration theories
//     all within +/-4us. Coupled latency/launch-structure region.
// ---------------------------------------------------------------------

// ---------------- prep: dequant (LDS codebook) + cast x ----------------
__global__ __launch_bounds__(512) void prep_kernel(
        const float* __restrict__ x, unsigned short* __restrict__ xb,
        const int* __restrict__ ig, const float* __restrict__ cbg,
        const float* __restrict__ sg, unsigned short* __restrict__ wg,
        const int* __restrict__ iu, const float* __restrict__ cbu,
        const float* __restrict__ su, unsigned short* __restrict__ wu,
        const int* __restrict__ idn, const float* __restrict__ cbd,
        const float* __restrict__ sd, unsigned short* __restrict__ wd) {
    __shared__ unsigned short cbl[4096 * 8];   // 64 KB bf16 codebook
    const int b = blockIdx.x;
    const int tid = threadIdx.x;

    if (b >= 528) {                            // ---- cast x ----
        int t = (b - 528) * 512 + tid;
        const float4* x4 = (const float4*)x;
        float4 a = x4[2 * t];
        float4 c = x4[2 * t + 1];
        uint4 o;
        o.x = f2bf(a.x) | ((unsigned int)f2bf(a.y) << 16);
        o.y = f2bf(a.z) | ((unsigned int)f2bf(a.w) << 16);
        o.z = f2bf(c.x) | ((unsigned int)f2bf(c.y) << 16);
        o.w = f2bf(c.z) | ((unsigned int)f2bf(c.w) << 16);
        ((uint4*)xb)[t] = o;
        return;
    }

    const int mat = b / 176;
    const int bl  = b % 176;
    const int* idx; const float* cb; const float* scale; unsigned short* w; int ncol8;
    if (mat == 0)      { idx = ig;  cb = cbg; scale = sg; w = wg; ncol8 = HIDDEN / 8; }
    else if (mat == 1) { idx = iu;  cb = cbu; scale = su; w = wu; ncol8 = HIDDEN / 8; }
    else               { idx = idn; cb = cbd; scale = sd; w = wd; ncol8 = INTER / 8; }

    const size_t base = (size_t)bl * 8192;

    // batched idx/scale preload (R14): HBM chains hide under staging
    int   ids[16];
    float ss[16];
#pragma unroll
    for (int i = 0; i < 16; ++i) {
        size_t t = base + i * 512 + tid;
        ids[i] = idx[t];
        ss[i]  = scale[t / ncol8];
    }

    // stage fp32 codebook -> bf16 LDS
#pragma unroll
    for (int i = 0; i < 8; ++i) {
        int r = i * 512 + tid;
        const float4* c4 = (const float4*)(cb + ((size_t)r << 3));
        float4 a = c4[0];
        float4 c = c4[1];
        uint4 o;
        o.x = f2bf(a.x) | ((unsigned int)f2bf(a.y) << 16);
        o.y = f2bf(a.z) | ((unsigned int)f2bf(a.w) << 16);
        o.z = f2bf(c.x) | ((unsigned int)f2bf(c.y) << 16);
        o.w = f2bf(c.z) | ((unsigned int)f2bf(c.w) << 16);
        ((uint4*)cbl)[r] = o;
    }
    __syncthreads();

    // 16 independent gather->scale->store chains (stride-512 layout:
    // lane-interleaved 16B stores = one contiguous 8KB wave-store)
#pragma unroll
    for (int i = 0; i < 16; ++i) {
        size_t t = base + i * 512 + tid;
        const unsigned short* cw = cbl + ((unsigned)ids[i] << 3);
        uint4 cv = *(const uint4*)cw;
        float s = ss[i];
        unsigned int ww[4];
#pragma unroll
        for (int j = 0; j < 4; ++j) {
            unsigned int pair = (&cv.x)[j];
            float lo = __uint_as_float(pair << 16) * s;
            float hi = __uint_as_float(pair & 0xFFFF0000u) * s;
            ww[j] = f2bf(lo) | ((unsigned int)f2bf(hi) << 16);
        }
        uint4 o = {ww[0], ww[1], ww[2], ww[3]};
        ((uint4*)w)[t] = o;
    }
}

__device__ __forceinline__ void decode_block(int bid, int nblocks_m, int nblocks_n,
                                             int gN, int* mb, int* nb) {
    int gw = nblocks_m * gN;
    int group = bid / gw;
    int inb = bid % gw;
    int gn = group * gN;
    int width = (nblocks_n - gn < gN) ? (nblocks_n - gn) : gN;
    *mb = inb / width;
    *nb = gn + inb % width;
}

// ---------------- GEMM1: H = silu(X Wg^T) * (X Wu^T), bf16 out ----------------
// R0-exact verified kernel: 128x128, 256 thr, (256,2), single-buf 2-barrier.
__global__ __launch_bounds__(256, 2) void gemm1_kernel(const unsigned short* __restrict__ X,
                                                       const unsigned short* __restrict__ Wg,
                                                       const unsigned short* __restrict__ Wu,
                                                       unsigned short* __restrict__ H) {
    __shared__ unsigned short As[BM * BK];
    __shared__ unsigned short Bgs[BN * BK];
    __shared__ unsigned short Bus[BN * BK];

    const int tid  = threadIdx.x;
    const int lane = tid & 63;
    const int wave = tid >> 6;
    int mb, nb;
    decode_block(blockIdx.x, TOKENS / BM, INTER / BN, 4, &mb, &nb);
    const int m0 = mb * BM;
    const int n0 = nb * BN;

    const int srow = tid >> 3;
    const int scol = (tid & 7) << 3;
    const int gcol = (((tid & 7) ^ (srow & 7))) << 3;

    const int wr = wave >> 1;
    const int wc = wave & 1;
    const int ln15 = lane & 15;
    const int lq = lane >> 4;
    const int swr = ln15 & 7;

    f32x4 accg[4][4], accu[4][4];
    const f32x4 z = {0.f, 0.f, 0.f, 0.f};
    for (int i = 0; i < 4; ++i)
        for (int j = 0; j < 4; ++j) { accg[i][j] = z; accu[i][j] = z; }

    for (int kt = 0; kt < HIDDEN / BK; ++kt) {
        const int k0 = kt * BK;
        __syncthreads();
#pragma unroll
        for (int i = 0; i < 4; ++i) {
            const int r = i * 32 + srow;
            GLDS(X  + (size_t)(m0 + r) * HIDDEN + k0 + gcol, As  + r * BK + scol);
            GLDS(Wg + (size_t)(n0 + r) * HIDDEN + k0 + gcol, Bgs + r * BK + scol);
            GLDS(Wu + (size_t)(n0 + r) * HIDDEN + k0 + gcol, Bus + r * BK + scol);
        }
        __syncthreads();
#pragma unroll
        for (int ks = 0; ks < 2; ++ks) {
            bf16x8 af[4], bg[4], bu[4];
            const int pofs = (((ks * 4 + lq) ^ swr)) << 3;
#pragma unroll
            for (int im = 0; im < 4; ++im)
                af[im] = *(const bf16x8*)(As + (wr * 64 + im * 16 + ln15) * BK + pofs);
#pragma unroll
            for (int in = 0; in < 4; ++in) {
                bg[in] = *(const bf16x8*)(Bgs + (wc * 64 + in * 16 + ln15) * BK + pofs);
                bu[in] = *(const bf16x8*)(Bus + (wc * 64 + in * 16 + ln15) * BK + pofs);
            }
#pragma unroll
            for (int im = 0; im < 4; ++im)
#pragma unroll
                for (int in = 0; in < 4; ++in) {
                    accg[im][in] = __builtin_amdgcn_mfma_f32_16x16x32_bf16(af[im], bg[in], accg[im][in], 0, 0, 0);
                    accu[im][in] = __builtin_amdgcn_mfma_f32_16x16x32_bf16(af[im], bu[in], accu[im][in], 0, 0, 0);
                }
        }
    }

#pragma unroll
    for (int im = 0; im < 4; ++im)
#pragma unroll
        for (int in = 0; in < 4; ++in) {
            const int row = m0 + wr * 64 + im * 16 + lq * 4;
            const int col = n0 + wc * 64 + in * 16 + ln15;
#pragma unroll
            for (int r = 0; r < 4; ++r) {
                float g = accg[im][in][r];
                float u = accu[im][in][r];
                float h = g * (1.0f / (1.0f + __expf(-g))) * u;
                H[(size_t)(row + r) * INTER + col] = f2bf(h);
            }
        }
}

// ---------------- GEMM2: Out = H Wd^T, fp32 out ----------------
// Counted-vmcnt double-buffered pipeline @ 2 blocks/CU (R11); group 2 (R12).
__global__ __launch_bounds__(256, 2) void gemm2_kernel(const unsigned short* __restrict__ Hin,
                                                       const unsigned short* __restrict__ Wd,
                                                       float* __restrict__ Out) {
    __shared__ unsigned short As[2][BM * BK];   // 32 KB
    __shared__ unsigned short Bs[2][BN * BK];   // 32 KB

    const int tid  = threadIdx.x;
    const int lane = tid & 63;
    const int wave = tid >> 6;
    int mb, nb;
    decode_block(blockIdx.x, TOKENS / BM, HIDDEN / BN, 2, &mb, &nb);
    const int m0 = mb * BM;
    const int n0 = nb * BN;

    const int srow = tid >> 3;
    const int scol = (tid & 7) << 3;
    const int gcol = (((tid & 7) ^ (srow & 7))) << 3;

    const int wr = wave >> 1;
    const int wc = wave & 1;
    const int ln15 = lane & 15;
    const int lq = lane >> 4;
    const int swr = ln15 & 7;

    f32x4 acc[4][4];
    const f32x4 z = {0.f, 0.f, 0.f, 0.f};
    for (int i = 0; i < 4; ++i)
        for (int j = 0; j < 4; ++j) acc[i][j] = z;

    // 8 GLDS per thread per K-tile: A x4, B x4
#define STAGE2(buf, kt) do {                                                        \
        const int k0_ = (kt) * BK;                                                  \
        _Pragma("unroll")                                                           \
        for (int i_ = 0; i_ < 4; ++i_) {                                            \
            const int r_ = i_ * 32 + srow;                                          \
            GLDS(Hin + (size_t)(m0 + r_) * INTER + k0_ + gcol,                      \
                 &As[buf][r_ * BK + scol]);                                         \
        }                                                                           \
        _Pragma("unroll")                                                           \
        for (int i_ = 0; i_ < 4; ++i_) {                                            \
            const int r_ = i_ * 32 + srow;                                          \
            GLDS(Wd + (size_t)(n0 + r_) * INTER + k0_ + gcol,                       \
                 &Bs[buf][r_ * BK + scol]);                                         \
        }                                                                           \
    } while (0)

    STAGE2(0, 0);
    STAGE2(1, 1);                       // 16 loads in flight per thread

    for (int t = 0; t < NT2; ++t) {
        const int cur = t & 1;
        if (t + 1 < NT2) {
            asm volatile("s_waitcnt vmcnt(8)" ::: "memory");
        } else {
            asm volatile("s_waitcnt vmcnt(0)" ::: "memory");
        }
        __builtin_amdgcn_s_barrier();   // all waves' tile-t data visible

        // ---- ks = 0 ----
        bf16x8 a0[4], b0[4];
        {
            const int pofs = ((lq ^ swr)) << 3;
#pragma unroll
            for (int im = 0; im < 4; ++im)
                a0[im] = *(const bf16x8*)(&As[cur][(wr * 64 + im * 16 + ln15) * BK + pofs]);
#pragma unroll
            for (int in = 0; in < 4; ++in)
                b0[in] = *(const bf16x8*)(&Bs[cur][(wc * 64 + in * 16 + ln15) * BK + pofs]);
        }
#pragma unroll
        for (int im = 0; im < 4; ++im)
#pragma unroll
            for (int in = 0; in < 4; ++in)
                acc[im][in] = __builtin_amdgcn_mfma_f32_16x16x32_bf16(a0[im], b0[in], acc[im][in], 0, 0, 0);

        // ---- ks = 1 ----
        bf16x8 a1[4], b1[4];
        {
            const int pofs = (((4 + lq) ^ swr)) << 3;
#pragma unroll
            for (int im = 0; im < 4; ++im)
                a1[im] = *(const bf16x8*)(&As[cur][(wr * 64 + im * 16 + ln15) * BK + pofs]);
#pragma unroll
            for (int in = 0; in < 4; ++in)
                b1[in] = *(const bf16x8*)(&Bs[cur][(wc * 64 + in * 16 + ln15) * BK + pofs]);
        }
        asm volatile("s_waitcnt lgkmcnt(0)" ::: "memory");  // my LDS reads done
        __builtin_amdgcn_s_barrier();                        // everyone's reads done
        if (t + 2 < NT2) STAGE2(cur, t + 2);  // overwrite freed buf under ks1 MFMAs
#pragma unroll
        for (int im = 0; im < 4; ++im)
#pragma unroll
            for (int in = 0; in < 4; ++in)
                acc[im][in] = __builtin_amdgcn_mfma_f32_16x16x32_bf16(a1[im], b1[in], acc[im][in], 0, 0, 0);
    }
#undef STAGE2

#pragma unroll
    for (int im = 0; im < 4; ++im)
#pragma unroll
        for (int in = 0; in < 4; ++in) {
            const int row = m0 + wr * 64 + im * 16 + lq * 4;
            const int col = n0 + wc * 64 + in * 16 + ln15;
#pragma unroll
            for (int r = 0; r < 4; ++r)
                Out[(size_t)(row + r) * HIDDEN + col] = acc[im][in][r];
        }
}

extern "C" void kernel_launch(void* const* d_in, const int* in_sizes, int n_in,
                              void* d_out, int out_size, void* d_ws, size_t ws_size,
                              hipStream_t stream) {
    (void)in_sizes; (void)n_in; (void)out_size; (void)ws_size;

    const float* x   = (const float*)d_in[0];
    const float* cbg = (const float*)d_in[1];
    const int*   ig  = (const int*)d_in[2];
    const float* sg  = (const float*)d_in[3];
    const float* cbu = (const float*)d_in[4];
    const int*   iu  = (const int*)d_in[5];
    const float* su  = (const float*)d_in[6];
    const float* cbd = (const float*)d_in[7];
    const int*   idn = (const int*)d_in[8];
    const float* sd  = (const float*)d_in[9];
    float* out = (float*)d_out;

    char* p = (char*)d_ws;
    unsigned short* Xb = (unsigned short*)p; p += (size_t)TOKENS * HIDDEN * 2;
    unsigned short* Wg = (unsigned short*)p; p += (size_t)INTER * HIDDEN * 2;
    unsigned short* Wu = (unsigned short*)p; p += (size_t)INTER * HIDDEN * 2;
    unsigned short* Wd = (unsigned short*)p; p += (size_t)HIDDEN * INTER * 2;
    unsigned short* H  = (unsigned short*)p; p += (size_t)TOKENS * INTER * 2;

    prep_kernel<<<dim3(528 + 2048), dim3(512), 0, stream>>>(
        x, Xb, ig, cbg, sg, Wg, iu, cbu, su, Wu, idn, cbd, sd, Wd);

    gemm1_kernel<<<dim3((TOKENS / BM) * (INTER / BN)), dim3(256), 0, stream>>>(Xb, Wg, Wu, H);
    gemm2_kernel<<<dim3((TOKENS / BM) * (HIDDEN / BN)), dim3(256), 0, stream>>>(H, Wd, out);
}

// Round 13
// 363.400 us; speedup vs baseline: 1.0320x; 1.0058x over previous
//
#include <hip/hip_runtime.h>

#define HIDDEN 2048
#define INTER  5632
#define TOKENS 4096

#define BM 128
#define BN 128
#define BK 64
#define NT2 (INTER / BK)   // 88 K-tiles for gemm2

using bf16x8 = __attribute__((ext_vector_type(8))) __bf16;
using f32x4  = __attribute__((ext_vector_type(4))) float;

__device__ __forceinline__ unsigned short f2bf(float f) {
    unsigned int u = __float_as_uint(f);
    u += 0x7FFFu + ((u >> 16) & 1u);
    return (unsigned short)(u >> 16);
}

#define GLDS(gptr, lptr) \
    __builtin_amdgcn_global_load_lds((__attribute__((address_space(1))) void*)(gptr), \
                                     (__attribute__((address_space(3))) void*)(lptr), 16, 0, 0)

// Journal (final):
// R2: XOR-swizzle conflict-free w/ 16x16 frags. R5: group-raster FETCH -30%.
// R8: 32x32 frags 4-way bank-conflict at BK=64 — 16x16 only. R3: (256,3)
// gemm1 spills. R4: BK=32 dbuf regressed. R6: barrier-free glds UNSAFE.
// R9 FAILED: 8-phase port @1blk/CU: 48->31%, 176->252us.
// R10 FAILED: min-2-phase 256x128 @1blk/CU: 36%, 219us. 128KB-LDS
//   geometries kill the 2-blk/CU de-phasing that carries 49%.
// R11: gemm2 counted-vmcnt dbuf: neutral (kept — no cost).
// R12 DIAG: +1 gemm1 launch = +45us (dispatch-round tails first-order);
//   prep,gemm2 each <109us, sum ~188 incl gaps.
// R13 FAILED: L2-gather prep +12us (lane-divergent gather >> LDS gather).
// R14: ILP-16 idx preload ~0 (prep not idx-chain-latency-bound).
// R15: Wd->gemm1 tail costs +4.1us on gemm1; cast-split prep +8.9us rest.
// R16 FAILED: Wd was FREE under cast's BW-bound overlap — work overlapping
//   a BW-bound co-resident phase has zero marginal cost; don't relocate.
// R17 FAILED: quad-code prep +4us (lost wave-level store coalescing).
// R19 FAILED CORRECTNESS: single cooperative mega-kernel (512 blk,
//   grid.sync between phases) — nondeterministic absmax (race):
//   cross-XCD hand-off via plain stores+threadfence+grid.sync+GLDS reads
//   is not coherent on per-XCD-L2 hardware (Guideline 16). Reverted.
// R20: verified best composition resubmitted (R6/R18 bytes). Verified
//   results for these bytes: 362.1 (R3), 362.0 (R6), 365.5 (R10).
// R21 (this round): infra failure in R20's run ("container failed
//   twice") — no kernel evidence produced; clean resubmission.
//   Plateau 362.0-365.5us (run noise +/-3). NOT a HW roofline (gemm1 49%
//   MfmaUtil / 14% HBM): it is the 2-barrier-vmcnt(0) structure's ceiling
//   at this grid geometry; all tested escapes measured negative.
// ---------------------------------------------------------------------

// ---------------- prep: dequant (LDS codebook) + cast x ----------------
__global__ __launch_bounds__(512) void prep_kernel(
        const float* __restrict__ x, unsigned short* __restrict__ xb,
        const int* __restrict__ ig, const float* __restrict__ cbg,
        const float* __restrict__ sg, unsigned short* __restrict__ wg,
        const int* __restrict__ iu, const float* __restrict__ cbu,
        const float* __restrict__ su, unsigned short* __restrict__ wu,
        const int* __restrict__ idn, const float* __restrict__ cbd,
        const float* __restrict__ sd, unsigned short* __restrict__ wd) {
    __shared__ unsigned short cbl[4096 * 8];   // 64 KB bf16 codebook
    const int b = blockIdx.x;
    const int tid = threadIdx.x;

    if (b >= 528) {                            // ---- cast x ----
        int t = (b - 528) * 512 + tid;
        const float4* x4 = (const float4*)x;
        float4 a = x4[2 * t];
        float4 c = x4[2 * t + 1];
        uint4 o;
        o.x = f2bf(a.x) | ((unsigned int)f2bf(a.y) << 16);
        o.y = f2bf(a.z) | ((unsigned int)f2bf(a.w) << 16);
        o.z = f2bf(c.x) | ((unsigned int)f2bf(c.y) << 16);
        o.w = f2bf(c.z) | ((unsigned int)f2bf(c.w) << 16);
        ((uint4*)xb)[t] = o;
        return;
    }

    const int mat = b / 176;
    const int bl  = b % 176;
    const int* idx; const float* cb; const float* scale; unsigned short* w; int ncol8;
    if (mat == 0)      { idx = ig;  cb = cbg; scale = sg; w = wg; ncol8 = HIDDEN / 8; }
    else if (mat == 1) { idx = iu;  cb = cbu; scale = su; w = wu; ncol8 = HIDDEN / 8; }
    else               { idx = idn; cb = cbd; scale = sd; w = wd; ncol8 = INTER / 8; }

    const size_t base = (size_t)bl * 8192;

    // batched idx/scale preload (R14): HBM chains hide under staging
    int   ids[16];
    float ss[16];
#pragma unroll
    for (int i = 0; i < 16; ++i) {
        size_t t = base + i * 512 + tid;
        ids[i] = idx[t];
        ss[i]  = scale[t / ncol8];
    }

    // stage fp32 codebook -> bf16 LDS
#pragma unroll
    for (int i = 0; i < 8; ++i) {
        int r = i * 512 + tid;
        const float4* c4 = (const float4*)(cb + ((size_t)r << 3));
        float4 a = c4[0];
        float4 c = c4[1];
        uint4 o;
        o.x = f2bf(a.x) | ((unsigned int)f2bf(a.y) << 16);
        o.y = f2bf(a.z) | ((unsigned int)f2bf(a.w) << 16);
        o.z = f2bf(c.x) | ((unsigned int)f2bf(c.y) << 16);
        o.w = f2bf(c.z) | ((unsigned int)f2bf(c.w) << 16);
        ((uint4*)cbl)[r] = o;
    }
    __syncthreads();

    // 16 independent gather->scale->store chains (stride-512 layout:
    // lane-interleaved 16B stores = one contiguous 8KB wave-store)
#pragma unroll
    for (int i = 0; i < 16; ++i) {
        size_t t = base + i * 512 + tid;
        const unsigned short* cw = cbl + ((unsigned)ids[i] << 3);
        uint4 cv = *(const uint4*)cw;
        float s = ss[i];
        unsigned int ww[4];
#pragma unroll
        for (int j = 0; j < 4; ++j) {
            unsigned int pair = (&cv.x)[j];
            float lo = __uint_as_float(pair << 16) * s;
            float hi = __uint_as_float(pair & 0xFFFF0000u) * s;
            ww[j] = f2bf(lo) | ((unsigned int)f2bf(hi) << 16);
        }
        uint4 o = {ww[0], ww[1], ww[2], ww[3]};
        ((uint4*)w)[t] = o;
    }
}

__device__ __forceinline__ void decode_block(int bid, int nblocks_m, int nblocks_n,
                                             int gN, int* mb, int* nb) {
    int gw = nblocks_m * gN;
    int group = bid / gw;
    int inb = bid % gw;
    int gn = group * gN;
    int width = (nblocks_n - gn < gN) ? (nblocks_n - gn) : gN;
    *mb = inb / width;
    *nb = gn + inb % width;
}

// ---------------- GEMM1: H = silu(X Wg^T) * (X Wu^T), bf16 out ----------------
// R0-exact verified kernel: 128x128, 256 thr, (256,2), single-buf 2-barrier.
__global__ __launch_bounds__(256, 2) void gemm1_kernel(const unsigned short* __restrict__ X,
                                                       const unsigned short* __restrict__ Wg,
                                                       const unsigned short* __restrict__ Wu,
                                                       unsigned short* __restrict__ H) {
    __shared__ unsigned short As[BM * BK];
    __shared__ unsigned short Bgs[BN * BK];
    __shared__ unsigned short Bus[BN * BK];

    const int tid  = threadIdx.x;
    const int lane = tid & 63;
    const int wave = tid >> 6;
    int mb, nb;
    decode_block(blockIdx.x, TOKENS / BM, INTER / BN, 4, &mb, &nb);
    const int m0 = mb * BM;
    const int n0 = nb * BN;

    const int srow = tid >> 3;
    const int scol = (tid & 7) << 3;
    const int gcol = (((tid & 7) ^ (srow & 7))) << 3;

    const int wr = wave >> 1;
    const int wc = wave & 1;
    const int ln15 = lane & 15;
    const int lq = lane >> 4;
    const int swr = ln15 & 7;

    f32x4 accg[4][4], accu[4][4];
    const f32x4 z = {0.f, 0.f, 0.f, 0.f};
    for (int i = 0; i < 4; ++i)
        for (int j = 0; j < 4; ++j) { accg[i][j] = z; accu[i][j] = z; }

    for (int kt = 0; kt < HIDDEN / BK; ++kt) {
        const int k0 = kt * BK;
        __syncthreads();
#pragma unroll
        for (int i = 0; i < 4; ++i) {
            const int r = i * 32 + srow;
            GLDS(X  + (size_t)(m0 + r) * HIDDEN + k0 + gcol, As  + r * BK + scol);
            GLDS(Wg + (size_t)(n0 + r) * HIDDEN + k0 + gcol, Bgs + r * BK + scol);
            GLDS(Wu + (size_t)(n0 + r) * HIDDEN + k0 + gcol, Bus + r * BK + scol);
        }
        __syncthreads();
#pragma unroll
        for (int ks = 0; ks < 2; ++ks) {
            bf16x8 af[4], bg[4], bu[4];
            const int pofs = (((ks * 4 + lq) ^ swr)) << 3;
#pragma unroll
            for (int im = 0; im < 4; ++im)
                af[im] = *(const bf16x8*)(As + (wr * 64 + im * 16 + ln15) * BK + pofs);
#pragma unroll
            for (int in = 0; in < 4; ++in) {
                bg[in] = *(const bf16x8*)(Bgs + (wc * 64 + in * 16 + ln15) * BK + pofs);
                bu[in] = *(const bf16x8*)(Bus + (wc * 64 + in * 16 + ln15) * BK + pofs);
            }
#pragma unroll
            for (int im = 0; im < 4; ++im)
#pragma unroll
                for (int in = 0; in < 4; ++in) {
                    accg[im][in] = __builtin_amdgcn_mfma_f32_16x16x32_bf16(af[im], bg[in], accg[im][in], 0, 0, 0);
                    accu[im][in] = __builtin_amdgcn_mfma_f32_16x16x32_bf16(af[im], bu[in], accu[im][in], 0, 0, 0);
                }
        }
    }

#pragma unroll
    for (int im = 0; im < 4; ++im)
#pragma unroll
        for (int in = 0; in < 4; ++in) {
            const int row = m0 + wr * 64 + im * 16 + lq * 4;
            const int col = n0 + wc * 64 + in * 16 + ln15;
#pragma unroll
            for (int r = 0; r < 4; ++r) {
                float g = accg[im][in][r];
                float u = accu[im][in][r];
                float h = g * (1.0f / (1.0f + __expf(-g))) * u;
                H[(size_t)(row + r) * INTER + col] = f2bf(h);
            }
        }
}

// ---------------- GEMM2: Out = H Wd^T, fp32 out ----------------
// Counted-vmcnt double-buffered pipeline @ 2 blocks/CU (R11); group 2 (R12).
__global__ __launch_bounds__(256, 2) void gemm2_kernel(const unsigned short* __restrict__ Hin,
                                                       const unsigned short* __restrict__ Wd,
                                                       float* __restrict__ Out) {
    __shared__ unsigned short As[2][BM * BK];   // 32 KB
    __shared__ unsigned short Bs[2][BN * BK];   // 32 KB

    const int tid  = threadIdx.x;
    const int lane = tid & 63;
    const int wave = tid >> 6;
    int mb, nb;
    decode_block(blockIdx.x, TOKENS / BM, HIDDEN / BN, 2, &mb, &nb);
    const int m0 = mb * BM;
    const int n0 = nb * BN;

    const int srow = tid >> 3;
    const int scol = (tid & 7) << 3;
    const int gcol = (((tid & 7) ^ (srow & 7))) << 3;

    const int wr = wave >> 1;
    const int wc = wave & 1;
    const int ln15 = lane & 15;
    const int lq = lane >> 4;
    const int swr = ln15 & 7;

    f32x4 acc[4][4];
    const f32x4 z = {0.f, 0.f, 0.f, 0.f};
    for (int i = 0; i < 4; ++i)
        for (int j = 0; j < 4; ++j) acc[i][j] = z;

    // 8 GLDS per thread per K-tile: A x4, B x4
#define STAGE2(buf, kt) do {                                                        \
        const int k0_ = (kt) * BK;                                                  \
        _Pragma("unroll")                                                           \
        for (int i_ = 0; i_ < 4; ++i_) {                                            \
            const int r_ = i_ * 32 + srow;                                          \
            GLDS(Hin + (size_t)(m0 + r_) * INTER + k0_ + gcol,                      \
                 &As[buf][r_ * BK + scol]);                                         \
        }                                                                           \
        _Pragma("unroll")                                                           \
        for (int i_ = 0; i_ < 4; ++i_) {                                            \
            const int r_ = i_ * 32 + srow;                                          \
            GLDS(Wd + (size_t)(n0 + r_) * INTER + k0_ + gcol,                       \
                 &Bs[buf][r_ * BK + scol]);                                         \
        }                                                                           \
    } while (0)

    STAGE2(0, 0);
    STAGE2(1, 1);                       // 16 loads in flight per thread

    for (int t = 0; t < NT2; ++t) {
        const int cur = t & 1;
        if (t + 1 < NT2) {
            asm volatile("s_waitcnt vmcnt(8)" ::: "memory");
        } else {
            asm volatile("s_waitcnt vmcnt(0)" ::: "memory");
        }
        __builtin_amdgcn_s_barrier();   // all waves' tile-t data visible

        // ---- ks = 0 ----
        bf16x8 a0[4], b0[4];
        {
            const int pofs = ((lq ^ swr)) << 3;
#pragma unroll
            for (int im = 0; im < 4; ++im)
                a0[im] = *(const bf16x8*)(&As[cur][(wr * 64 + im * 16 + ln15) * BK + pofs]);
#pragma unroll
            for (int in = 0; in < 4; ++in)
                b0[in] = *(const bf16x8*)(&Bs[cur][(wc * 64 + in * 16 + ln15) * BK + pofs]);
        }
#pragma unroll
        for (int im = 0; im < 4; ++im)
#pragma unroll
            for (int in = 0; in < 4; ++in)
                acc[im][in] = __builtin_amdgcn_mfma_f32_16x16x32_bf16(a0[im], b0[in], acc[im][in], 0, 0, 0);

        // ---- ks = 1 ----
        bf16x8 a1[4], b1[4];
        {
            const int pofs = (((4 + lq) ^ swr)) << 3;
#pragma unroll
            for (int im = 0; im < 4; ++im)
                a1[im] = *(const bf16x8*)(&As[cur][(wr * 64 + im * 16 + ln15) * BK + pofs]);
#pragma unroll
            for (int in = 0; in < 4; ++in)
                b1[in] = *(const bf16x8*)(&Bs[cur][(wc * 64 + in * 16 + ln15) * BK + pofs]);
        }
        asm volatile("s_waitcnt lgkmcnt(0)" ::: "memory");  // my LDS reads done
        __builtin_amdgcn_s_barrier();                        // everyone's reads done
        if (t + 2 < NT2) STAGE2(cur, t + 2);  // overwrite freed buf under ks1 MFMAs
#pragma unroll
        for (int im = 0; im < 4; ++im)
#pragma unroll
            for (int in = 0; in < 4; ++in)
                acc[im][in] = __builtin_amdgcn_mfma_f32_16x16x32_bf16(a1[im], b1[in], acc[im][in], 0, 0, 0);
    }
#undef STAGE2

#pragma unroll
    for (int im = 0; im < 4; ++im)
#pragma unroll
        for (int in = 0; in < 4; ++in) {
            const int row = m0 + wr * 64 + im * 16 + lq * 4;
            const int col = n0 + wc * 64 + in * 16 + ln15;
#pragma unroll
            for (int r = 0; r < 4; ++r)
                Out[(size_t)(row + r) * HIDDEN + col] = acc[im][in][r];
        }
}

extern "C" void kernel_launch(void* const* d_in, const int* in_sizes, int n_in,
                              void* d_out, int out_size, void* d_ws, size_t ws_size,
                              hipStream_t stream) {
    (void)in_sizes; (void)n_in; (void)out_size; (void)ws_size;

    const float* x   = (const float*)d_in[0];
    const float* cbg = (const float*)d_in[1];
    const int*   ig  = (const int*)d_in[2];
    const float* sg  = (const float*)d_in[3];
    const float* cbu = (const float*)d_in[4];
    const int*   iu  = (const int*)d_in[5];
    const float* su  = (const float*)d_in[6];
    const float* cbd = (const float*)d_in[7];
    const int*   idn = (const int*)d_in[8];
    const float* sd  = (const float*)d_in[9];
    float* out = (float*)d_out;

    char* p = (char*)d_ws;
    unsigned short* Xb = (unsigned short*)p; p += (size_t)TOKENS * HIDDEN * 2;
    unsigned short* Wg = (unsigned short*)p; p += (size_t)INTER * HIDDEN * 2;
    unsigned short* Wu = (unsigned short*)p; p += (size_t)INTER * HIDDEN * 2;
    unsigned short* Wd = (unsigned short*)p; p += (size_t)HIDDEN * INTER * 2;
    unsigned short* H  = (unsigned short*)p; p += (size_t)TOKENS * INTER * 2;

    prep_kernel<<<dim3(528 + 2048), dim3(512), 0, stream>>>(
        x, Xb, ig, cbg, sg, Wg, iu, cbu, su, Wu, idn, cbd, sd, Wd);

    gemm1_kernel<<<dim3((TOKENS / BM) * (INTER / BN)), dim3(256), 0, stream>>>(Xb, Wg, Wu, H);
    gemm2_kernel<<<dim3((TOKENS / BM) * (HIDDEN / BN)), dim3(256), 0, stream>>>(H, Wd, out);
}